// Round 1
// baseline (1488.609 us; speedup 1.0000x reference)
//
#include <hip/hip_runtime.h>
#include <hip/hip_bf16.h>

#define N_NODES 100000
#define N_EDGES 1600000
#define C_DIM 256
#define H_DIM 128
#define F_DIM 64

// ---------------------------------------------------------------------------
// Build CSR row_ptr from sorted COO edge_row via per-node binary search.
// row_ptr[i] = lower_bound(edge_row, i); row_ptr[N] = E (all values < N).
// ---------------------------------------------------------------------------
__global__ void build_row_ptr(const int* __restrict__ erow, int* __restrict__ row_ptr) {
    int i = blockIdx.x * blockDim.x + threadIdx.x;
    if (i > N_NODES) return;
    int lo = 0, hi = N_EDGES;
    while (lo < hi) {
        int mid = (lo + hi) >> 1;
        if (erow[mid] < i) lo = mid + 1; else hi = mid;
    }
    row_ptr[i] = lo;
}

// ---------------------------------------------------------------------------
// f32 GEMM: C[n,m] = sum_k A[n,k] * B[m,k]   (B is a [M,K] row-major weight)
// Tile: 64 rows x (16*TN) cols, BK=32, 256 threads, 4xTN microtile/thread.
// Column interleave (col = tx + 16*j) => conflict-free Bs reads + coalesced C.
// ---------------------------------------------------------------------------
template <int TN>
__global__ __launch_bounds__(256) void gemm_nt(const float* __restrict__ A,
                                               const float* __restrict__ B,
                                               float* __restrict__ C,
                                               int nrows, int K, int M) {
    constexpr int BN = 16 * TN;
    __shared__ float As[64][33];
    __shared__ float Bs[BN][33];

    const int tid = threadIdx.x;
    const int tx = tid & 15;    // column lane: cols tx + 16*j
    const int ty = tid >> 4;    // row lane:    rows ty + 16*i
    const long row0 = (long)blockIdx.x * 64;
    const int col0 = blockIdx.y * BN;

    float acc[4][TN];
#pragma unroll
    for (int i = 0; i < 4; i++)
#pragma unroll
        for (int j = 0; j < TN; j++) acc[i][j] = 0.f;

    for (int k0 = 0; k0 < K; k0 += 32) {
        // Stage A tile: 64x32, 8 elems/thread, coalesced (c = off&31).
#pragma unroll
        for (int s = 0; s < 8; s++) {
            int off = s * 256 + tid;
            int r = off >> 5, c = off & 31;
            long gr = row0 + r;
            As[r][c] = (gr < nrows) ? A[gr * K + k0 + c] : 0.f;
        }
        // Stage B tile: BNx32.
#pragma unroll
        for (int s = 0; s < TN * 2; s++) {
            int off = s * 256 + tid;
            int r = off >> 5, c = off & 31;
            Bs[r][c] = B[(long)(col0 + r) * K + k0 + c];
        }
        __syncthreads();

#pragma unroll
        for (int kk = 0; kk < 32; kk++) {
            float a[4], b[TN];
#pragma unroll
            for (int i = 0; i < 4; i++) a[i] = As[ty + 16 * i][kk];
#pragma unroll
            for (int j = 0; j < TN; j++) b[j] = Bs[tx + 16 * j][kk];
#pragma unroll
            for (int i = 0; i < 4; i++)
#pragma unroll
                for (int j = 0; j < TN; j++) acc[i][j] += a[i] * b[j];
        }
        __syncthreads();
    }

#pragma unroll
    for (int i = 0; i < 4; i++) {
        long gr = row0 + ty + 16 * i;
        if (gr < nrows) {
#pragma unroll
            for (int j = 0; j < TN; j++)
                C[gr * M + col0 + tx + 16 * j] = acc[i][j];
        }
    }
}

// ---------------------------------------------------------------------------
// SpMM: out[i,h] = sum_{e in row i} val[e] * Z[col[e], h]   (+ optional ReLU)
// One node per H-thread group; feature dim coalesced. Edge metadata loads are
// wave-uniform (scalar path).
// ---------------------------------------------------------------------------
template <int H, bool RELU>
__global__ __launch_bounds__(256) void spmm_kernel(const int* __restrict__ row_ptr,
                                                   const int* __restrict__ ecol,
                                                   const float* __restrict__ eval_,
                                                   const float* __restrict__ Z,
                                                   float* __restrict__ out) {
    constexpr int NPB = 256 / H;
    int node = blockIdx.x * NPB + threadIdx.x / H;
    int h = threadIdx.x % H;
    if (node >= N_NODES) return;
    int start = row_ptr[node];
    int end = row_ptr[node + 1];
    float acc = 0.f;
    for (int e = start; e < end; e++) {
        int c = ecol[e];
        float v = eval_[e];
        acc += v * Z[(long)c * H + h];
    }
    if (RELU) acc = fmaxf(acc, 0.f);
    out[(long)node * H + h] = acc;
}

// ---------------------------------------------------------------------------
// Row softmax over F=64 columns. One 64-lane wave per row, 4 rows per block.
// ---------------------------------------------------------------------------
__global__ __launch_bounds__(256) void softmax64(float* __restrict__ out) {
    int row = blockIdx.x * 4 + (threadIdx.x >> 6);
    int lane = threadIdx.x & 63;
    if (row >= N_NODES) return;
    long idx = (long)row * 64 + lane;
    float x = out[idx];
    float m = x;
#pragma unroll
    for (int off = 32; off > 0; off >>= 1) m = fmaxf(m, __shfl_xor(m, off, 64));
    float e = expf(x - m);
    float s = e;
#pragma unroll
    for (int off = 32; off > 0; off >>= 1) s += __shfl_xor(s, off, 64);
    out[idx] = e / s;
}

extern "C" void kernel_launch(void* const* d_in, const int* in_sizes, int n_in,
                              void* d_out, int out_size, void* d_ws, size_t ws_size,
                              hipStream_t stream) {
    const float* X = (const float*)d_in[0];
    const int* erow = (const int*)d_in[1];
    const int* ecol = (const int*)d_in[2];
    const float* eval_ = (const float*)d_in[3];
    const float* W0 = (const float*)d_in[4];   // [128,256]
    const float* Wh0 = (const float*)d_in[5];  // [128,128]
    const float* W1 = (const float*)d_in[6];   // [64,128]
    float* out = (float*)d_out;                // [N,64]

    char* ws = (char*)d_ws;
    int* row_ptr = (int*)ws;
    ws += (((size_t)(N_NODES + 1) * sizeof(int)) + 255) & ~(size_t)255;
    float* bufA = (float*)ws;
    ws += (size_t)N_NODES * H_DIM * sizeof(float);
    float* bufB = (float*)ws;

    // CSR offsets (cheap; recomputed every call for graph-capture safety)
    build_row_ptr<<<(N_NODES + 256) / 256, 256, 0, stream>>>(erow, row_ptr);

    // Layer 0: bufA = X @ W0^T  [N,128]
    dim3 g1((N_NODES + 63) / 64, 1);
    gemm_nt<8><<<g1, 256, 0, stream>>>(X, W0, bufA, N_NODES, C_DIM, H_DIM);
    // bufB = relu(A_hat @ bufA)
    spmm_kernel<128, true><<<N_NODES / 2, 256, 0, stream>>>(row_ptr, ecol, eval_, bufA, bufB);

    // Hidden layer: bufA = bufB @ Wh0^T  [N,128]
    gemm_nt<8><<<g1, 256, 0, stream>>>(bufB, Wh0, bufA, N_NODES, H_DIM, H_DIM);
    // bufB = relu(A_hat @ bufA)
    spmm_kernel<128, true><<<N_NODES / 2, 256, 0, stream>>>(row_ptr, ecol, eval_, bufA, bufB);

    // Output layer: bufA = bufB @ W1^T  [N,64]
    gemm_nt<4><<<g1, 256, 0, stream>>>(bufB, W1, bufA, N_NODES, H_DIM, F_DIM);
    // out = A_hat @ bufA
    spmm_kernel<64, false><<<N_NODES / 4, 256, 0, stream>>>(row_ptr, ecol, eval_, bufA, out);

    // Softmax rows in place
    softmax64<<<N_NODES / 4, 256, 0, stream>>>(out);
}

// Round 3
// 949.060 us; speedup vs baseline: 1.5685x; 1.5685x over previous
//
#include <hip/hip_runtime.h>
#include <hip/hip_bf16.h>

#define N_NODES 100000
#define N_EDGES 1600000
#define C_DIM 256
#define H_DIM 128
#define F_DIM 64

typedef short bf16x8 __attribute__((ext_vector_type(8)));
typedef float f32x4 __attribute__((ext_vector_type(4)));
typedef unsigned short u16;
typedef u16 u16x8 __attribute__((ext_vector_type(8)));

__device__ __forceinline__ u16 f32_to_bf16(float f) {
    union { float f; unsigned int u; } v; v.f = f;
    unsigned int r = (v.u + 0x7FFFu + ((v.u >> 16) & 1u)) >> 16;  // RTNE
    return (u16)r;
}
__device__ __forceinline__ float bf16_to_f32(u16 b) {
    union { unsigned int u; float f; } v; v.u = ((unsigned int)b) << 16;
    return v.f;
}

// ---------------------------------------------------------------------------
// Build CSR row_ptr from sorted COO edge_row via per-node binary search.
// ---------------------------------------------------------------------------
__global__ void build_row_ptr(const int* __restrict__ erow, int* __restrict__ row_ptr) {
    int i = blockIdx.x * blockDim.x + threadIdx.x;
    if (i > N_NODES) return;
    int lo = 0, hi = N_EDGES;
    while (lo < hi) {
        int mid = (lo + hi) >> 1;
        if (erow[mid] < i) lo = mid + 1; else hi = mid;
    }
    row_ptr[i] = lo;
}

// ---------------------------------------------------------------------------
// MFMA GEMM with bf16x3 split for f32-equivalent accuracy.
// C[n,m] = sum_k A[n,k] * B[m,k];  A:[nrows,K] f32, B:[BN,K] f32, C:[nrows,BN].
// Block: 256 threads (4 waves, 2x2), tile 64 rows x BN cols, K-step 32.
// Each f32 split into bf16 hi + bf16 lo; 3 MFMAs: lo*hi + hi*lo + hi*hi.
// LDS rows padded to 40 u16 (80B): 16B-aligned ds_read_b128, ~2-way banks (free).
// Fragment map (m89-verified family): A/B lane l -> row l&15, k = (l>>4)*8+j;
// D lane l reg r -> row (l>>4)*4+r, col l&15.
// ---------------------------------------------------------------------------
template <int BN>
__global__ __launch_bounds__(256) void gemm_mfma(const float* __restrict__ A,
                                                 const float* __restrict__ B,
                                                 float* __restrict__ C,
                                                 int nrows, int K) {
    constexpr int NJ = BN / 32;     // 16-col frags per wave (wave covers BN/2 cols)
    __shared__ u16 AsH[64][40], AsL[64][40];
    __shared__ u16 BsH[BN][40], BsL[BN][40];

    const int tid = threadIdx.x;
    const long row0 = (long)blockIdx.x * 64;
    const int w = tid >> 6;
    const int wm = w >> 1;          // wave row group (0..1) -> 32 rows
    const int wn = w & 1;           // wave col group (0..1) -> BN/2 cols
    const int lc = tid & 15;        // lane col / frag row
    const int lq = (tid >> 4) & 3;  // lane quad within wave
    const int sr = tid >> 2;        // staging row (0..63)
    const int skc = (tid & 3) * 8;  // staging k offset

    f32x4 acc[2][NJ];
#pragma unroll
    for (int i = 0; i < 2; i++)
#pragma unroll
        for (int j = 0; j < NJ; j++) acc[i][j] = (f32x4)0.f;

    for (int k0 = 0; k0 < K; k0 += 32) {
        // --- stage A tile 64x32: 8 f32/thread, coalesced float4 pairs ---
        {
            float x[8];
            long gr = row0 + sr;
            if (gr < nrows) {
                const float* p = A + gr * K + k0 + skc;
                float4 u0 = *(const float4*)p;
                float4 u1 = *(const float4*)(p + 4);
                x[0] = u0.x; x[1] = u0.y; x[2] = u0.z; x[3] = u0.w;
                x[4] = u1.x; x[5] = u1.y; x[6] = u1.z; x[7] = u1.w;
            } else {
#pragma unroll
                for (int j = 0; j < 8; j++) x[j] = 0.f;
            }
            u16x8 h, l;
#pragma unroll
            for (int j = 0; j < 8; j++) {
                u16 hb = f32_to_bf16(x[j]);
                h[j] = hb;
                l[j] = f32_to_bf16(x[j] - bf16_to_f32(hb));
            }
            *(u16x8*)&AsH[sr][skc] = h;
            *(u16x8*)&AsL[sr][skc] = l;
        }
        // --- stage B tile BNx32 (always in bounds) ---
#pragma unroll
        for (int s = 0; s < BN / 64; s++) {
            int br = sr + 64 * s;
            const float* p = B + (long)br * K + k0 + skc;
            float4 u0 = *(const float4*)p;
            float4 u1 = *(const float4*)(p + 4);
            float x[8] = {u0.x, u0.y, u0.z, u0.w, u1.x, u1.y, u1.z, u1.w};
            u16x8 h, l;
#pragma unroll
            for (int j = 0; j < 8; j++) {
                u16 hb = f32_to_bf16(x[j]);
                h[j] = hb;
                l[j] = f32_to_bf16(x[j] - bf16_to_f32(hb));
            }
            *(u16x8*)&BsH[br][skc] = h;
            *(u16x8*)&BsL[br][skc] = l;
        }
        __syncthreads();

        // --- fragments + 3-term MFMA ---
        bf16x8 aH[2], aL[2], bH[NJ], bL[NJ];
#pragma unroll
        for (int mi = 0; mi < 2; mi++) {
            int r = wm * 32 + mi * 16 + lc;
            aH[mi] = *(const bf16x8*)&AsH[r][lq * 8];
            aL[mi] = *(const bf16x8*)&AsL[r][lq * 8];
        }
#pragma unroll
        for (int nj = 0; nj < NJ; nj++) {
            int r = wn * (BN / 2) + nj * 16 + lc;
            bH[nj] = *(const bf16x8*)&BsH[r][lq * 8];
            bL[nj] = *(const bf16x8*)&BsL[r][lq * 8];
        }
#pragma unroll
        for (int mi = 0; mi < 2; mi++)
#pragma unroll
            for (int nj = 0; nj < NJ; nj++) {
                acc[mi][nj] = __builtin_amdgcn_mfma_f32_16x16x32_bf16(aL[mi], bH[nj], acc[mi][nj], 0, 0, 0);
                acc[mi][nj] = __builtin_amdgcn_mfma_f32_16x16x32_bf16(aH[mi], bL[nj], acc[mi][nj], 0, 0, 0);
                acc[mi][nj] = __builtin_amdgcn_mfma_f32_16x16x32_bf16(aH[mi], bH[nj], acc[mi][nj], 0, 0, 0);
            }
        __syncthreads();
    }

    // --- store C (row guard; 16 consecutive cols per lane group = coalesced) ---
#pragma unroll
    for (int mi = 0; mi < 2; mi++)
#pragma unroll
        for (int nj = 0; nj < NJ; nj++) {
            int col = wn * (BN / 2) + nj * 16 + lc;
#pragma unroll
            for (int r4 = 0; r4 < 4; r4++) {
                long grow = row0 + wm * 32 + mi * 16 + lq * 4 + r4;
                if (grow < nrows) C[grow * BN + col] = acc[mi][nj][r4];
            }
        }
}

// ---------------------------------------------------------------------------
// SpMM: out[i,h] = sum_{e in row i} val[e] * Z[col[e], h]   (+ optional ReLU)
// ---------------------------------------------------------------------------
template <int H, bool RELU>
__global__ __launch_bounds__(256) void spmm_kernel(const int* __restrict__ row_ptr,
                                                   const int* __restrict__ ecol,
                                                   const float* __restrict__ eval_,
                                                   const float* __restrict__ Z,
                                                   float* __restrict__ out) {
    constexpr int NPB = 256 / H;
    int node = blockIdx.x * NPB + threadIdx.x / H;
    int h = threadIdx.x % H;
    if (node >= N_NODES) return;
    int start = row_ptr[node];
    int end = row_ptr[node + 1];
    float acc = 0.f;
    for (int e = start; e < end; e++) {
        int c = ecol[e];
        float v = eval_[e];
        acc += v * Z[(long)c * H + h];
    }
    if (RELU) acc = fmaxf(acc, 0.f);
    out[(long)node * H + h] = acc;
}

// ---------------------------------------------------------------------------
// Row softmax over F=64 columns. One 64-lane wave per row, 4 rows per block.
// ---------------------------------------------------------------------------
__global__ __launch_bounds__(256) void softmax64(float* __restrict__ out) {
    int row = blockIdx.x * 4 + (threadIdx.x >> 6);
    int lane = threadIdx.x & 63;
    if (row >= N_NODES) return;
    long idx = (long)row * 64 + lane;
    float x = out[idx];
    float m = x;
#pragma unroll
    for (int off = 32; off > 0; off >>= 1) m = fmaxf(m, __shfl_xor(m, off, 64));
    float e = expf(x - m);
    float s = e;
#pragma unroll
    for (int off = 32; off > 0; off >>= 1) s += __shfl_xor(s, off, 64);
    out[idx] = e / s;
}

extern "C" void kernel_launch(void* const* d_in, const int* in_sizes, int n_in,
                              void* d_out, int out_size, void* d_ws, size_t ws_size,
                              hipStream_t stream) {
    const float* X = (const float*)d_in[0];
    const int* erow = (const int*)d_in[1];
    const int* ecol = (const int*)d_in[2];
    const float* eval_ = (const float*)d_in[3];
    const float* W0 = (const float*)d_in[4];   // [128,256]
    const float* Wh0 = (const float*)d_in[5];  // [128,128]
    const float* W1 = (const float*)d_in[6];   // [64,128]
    float* out = (float*)d_out;                // [N,64]

    char* ws = (char*)d_ws;
    int* row_ptr = (int*)ws;
    ws += (((size_t)(N_NODES + 1) * sizeof(int)) + 255) & ~(size_t)255;
    float* bufA = (float*)ws;
    ws += (size_t)N_NODES * H_DIM * sizeof(float);
    float* bufB = (float*)ws;

    build_row_ptr<<<(N_NODES + 256) / 256, 256, 0, stream>>>(erow, row_ptr);

    dim3 g1((N_NODES + 63) / 64, 1);
    // Layer 0: bufA = X @ W0^T  [N,128]
    gemm_mfma<128><<<g1, 256, 0, stream>>>(X, W0, bufA, N_NODES, C_DIM);
    // bufB = relu(A_hat @ bufA)
    spmm_kernel<128, true><<<N_NODES / 2, 256, 0, stream>>>(row_ptr, ecol, eval_, bufA, bufB);

    // Hidden layer: bufA = bufB @ Wh0^T  [N,128]
    gemm_mfma<128><<<g1, 256, 0, stream>>>(bufB, Wh0, bufA, N_NODES, H_DIM);
    // bufB = relu(A_hat @ bufA)
    spmm_kernel<128, true><<<N_NODES / 2, 256, 0, stream>>>(row_ptr, ecol, eval_, bufA, bufB);

    // Output layer: bufA = bufB @ W1^T  [N,64]
    gemm_mfma<64><<<g1, 256, 0, stream>>>(bufB, W1, bufA, N_NODES, H_DIM);
    // out = A_hat @ bufA
    spmm_kernel<64, false><<<N_NODES / 4, 256, 0, stream>>>(row_ptr, ecol, eval_, bufA, out);

    softmax64<<<N_NODES / 4, 256, 0, stream>>>(out);
}

// Round 7
// 592.888 us; speedup vs baseline: 2.5108x; 1.6007x over previous
//
#include <hip/hip_runtime.h>
#include <hip/hip_bf16.h>

#define N_NODES 100000
#define N_EDGES 1600000
#define C_DIM 256
#define H_DIM 128
#define F_DIM 64

typedef short bf16x8 __attribute__((ext_vector_type(8)));
typedef float f32x4 __attribute__((ext_vector_type(4)));
typedef unsigned short u16;
typedef u16 u16x8 __attribute__((ext_vector_type(8)));

__device__ __forceinline__ u16 f32_to_bf16(float f) {
    union { float f; unsigned int u; } v; v.f = f;
    unsigned int r = (v.u + 0x7FFFu + ((v.u >> 16) & 1u)) >> 16;  // RTNE
    return (u16)r;
}
__device__ __forceinline__ float bf16_to_f32(u16 b) {
    union { unsigned int u; float f; } v; v.u = ((unsigned int)b) << 16;
    return v.f;
}

// ---------------------------------------------------------------------------
// Build CSR row_ptr from sorted COO edge_row via per-node binary search.
// ---------------------------------------------------------------------------
__global__ void build_row_ptr(const int* __restrict__ erow, int* __restrict__ row_ptr) {
    int i = blockIdx.x * blockDim.x + threadIdx.x;
    if (i > N_NODES) return;
    int lo = 0, hi = N_EDGES;
    while (lo < hi) {
        int mid = (lo + hi) >> 1;
        if (erow[mid] < i) lo = mid + 1; else hi = mid;
    }
    row_ptr[i] = lo;
}

// ---------------------------------------------------------------------------
// MFMA GEMM with bf16x3 split for f32-equivalent accuracy (unchanged r3).
// ---------------------------------------------------------------------------
template <int BN>
__global__ __launch_bounds__(256) void gemm_mfma(const float* __restrict__ A,
                                                 const float* __restrict__ B,
                                                 float* __restrict__ C,
                                                 int nrows, int K) {
    constexpr int NJ = BN / 32;
    __shared__ u16 AsH[64][40], AsL[64][40];
    __shared__ u16 BsH[BN][40], BsL[BN][40];

    const int tid = threadIdx.x;
    const long row0 = (long)blockIdx.x * 64;
    const int w = tid >> 6;
    const int wm = w >> 1;
    const int wn = w & 1;
    const int lc = tid & 15;
    const int lq = (tid >> 4) & 3;
    const int sr = tid >> 2;
    const int skc = (tid & 3) * 8;

    f32x4 acc[2][NJ];
#pragma unroll
    for (int i = 0; i < 2; i++)
#pragma unroll
        for (int j = 0; j < NJ; j++) acc[i][j] = (f32x4)0.f;

    for (int k0 = 0; k0 < K; k0 += 32) {
        {
            float x[8];
            long gr = row0 + sr;
            if (gr < nrows) {
                const float* p = A + gr * K + k0 + skc;
                float4 u0 = *(const float4*)p;
                float4 u1 = *(const float4*)(p + 4);
                x[0] = u0.x; x[1] = u0.y; x[2] = u0.z; x[3] = u0.w;
                x[4] = u1.x; x[5] = u1.y; x[6] = u1.z; x[7] = u1.w;
            } else {
#pragma unroll
                for (int j = 0; j < 8; j++) x[j] = 0.f;
            }
            u16x8 h, l;
#pragma unroll
            for (int j = 0; j < 8; j++) {
                u16 hb = f32_to_bf16(x[j]);
                h[j] = hb;
                l[j] = f32_to_bf16(x[j] - bf16_to_f32(hb));
            }
            *(u16x8*)&AsH[sr][skc] = h;
            *(u16x8*)&AsL[sr][skc] = l;
        }
#pragma unroll
        for (int s = 0; s < BN / 64; s++) {
            int br = sr + 64 * s;
            const float* p = B + (long)br * K + k0 + skc;
            float4 u0 = *(const float4*)p;
            float4 u1 = *(const float4*)(p + 4);
            float x[8] = {u0.x, u0.y, u0.z, u0.w, u1.x, u1.y, u1.z, u1.w};
            u16x8 h, l;
#pragma unroll
            for (int j = 0; j < 8; j++) {
                u16 hb = f32_to_bf16(x[j]);
                h[j] = hb;
                l[j] = f32_to_bf16(x[j] - bf16_to_f32(hb));
            }
            *(u16x8*)&BsH[br][skc] = h;
            *(u16x8*)&BsL[br][skc] = l;
        }
        __syncthreads();

        bf16x8 aH[2], aL[2], bH[NJ], bL[NJ];
#pragma unroll
        for (int mi = 0; mi < 2; mi++) {
            int r = wm * 32 + mi * 16 + lc;
            aH[mi] = *(const bf16x8*)&AsH[r][lq * 8];
            aL[mi] = *(const bf16x8*)&AsL[r][lq * 8];
        }
#pragma unroll
        for (int nj = 0; nj < NJ; nj++) {
            int r = wn * (BN / 2) + nj * 16 + lc;
            bH[nj] = *(const bf16x8*)&BsH[r][lq * 8];
            bL[nj] = *(const bf16x8*)&BsL[r][lq * 8];
        }
#pragma unroll
        for (int mi = 0; mi < 2; mi++)
#pragma unroll
            for (int nj = 0; nj < NJ; nj++) {
                acc[mi][nj] = __builtin_amdgcn_mfma_f32_16x16x32_bf16(aL[mi], bH[nj], acc[mi][nj], 0, 0, 0);
                acc[mi][nj] = __builtin_amdgcn_mfma_f32_16x16x32_bf16(aH[mi], bL[nj], acc[mi][nj], 0, 0, 0);
                acc[mi][nj] = __builtin_amdgcn_mfma_f32_16x16x32_bf16(aH[mi], bH[nj], acc[mi][nj], 0, 0, 0);
            }
        __syncthreads();
    }

#pragma unroll
    for (int mi = 0; mi < 2; mi++)
#pragma unroll
        for (int nj = 0; nj < NJ; nj++) {
            int col = wn * (BN / 2) + nj * 16 + lc;
#pragma unroll
            for (int r4 = 0; r4 < 4; r4++) {
                long grow = row0 + wm * 32 + mi * 16 + lq * 4 + r4;
                if (grow < nrows) C[grow * BN + col] = acc[mi][nj][r4];
            }
        }
}

// ---------------------------------------------------------------------------
// SpMM, wave-per-node with 4-deep MLP unroll.
// out[i,:] = sum_{e in row i} val[e] * Z[col[e],:]   (+ optional ReLU)
// One 64-lane wave owns one node; lane covers H/64 consecutive features
// (float2 at H=128). Edge loop processed in groups of 4 with tail masking
// (v=0, c=0) so 4 independent row-gathers are in flight per wave -> hides
// the ~200-900cy gather latency that bound the previous version.
// ---------------------------------------------------------------------------
template <int H, bool RELU>
__global__ __launch_bounds__(256) void spmm_wave(const int* __restrict__ rp,
                                                 const int* __restrict__ ecol,
                                                 const float* __restrict__ ev,
                                                 const float* __restrict__ Z,
                                                 float* __restrict__ out) {
    constexpr int VEC = H / 64;  // floats per lane
    int node = blockIdx.x * 4 + (threadIdx.x >> 6);
    if (node >= N_NODES) return;
    int lane = threadIdx.x & 63;
    int start = rp[node], end = rp[node + 1];

    float acc[VEC];
#pragma unroll
    for (int i = 0; i < VEC; i++) acc[i] = 0.f;

    for (int e = start; e < end; e += 4) {
        int c[4]; float v[4];
#pragma unroll
        for (int j = 0; j < 4; j++) {
            int ee = e + j;
            bool ok = ee < end;
            c[j] = ok ? ecol[ee] : 0;
            v[j] = ok ? ev[ee] : 0.f;
        }
        float z[4][VEC];
#pragma unroll
        for (int j = 0; j < 4; j++) {
            const float* p = Z + (long)c[j] * H + lane * VEC;
            if constexpr (VEC == 2) {
                float2 t = *(const float2*)p;
                z[j][0] = t.x; z[j][1] = t.y;
            } else {
                z[j][0] = *p;
            }
        }
#pragma unroll
        for (int j = 0; j < 4; j++)
#pragma unroll
            for (int i = 0; i < VEC; i++) acc[i] += v[j] * z[j][i];
    }

    if (RELU) {
#pragma unroll
        for (int i = 0; i < VEC; i++) acc[i] = fmaxf(acc[i], 0.f);
    }
    float* po = out + (long)node * H + lane * VEC;
    if constexpr (VEC == 2) {
        float2 t; t.x = acc[0]; t.y = acc[1];
        *(float2*)po = t;
    } else {
        *po = acc[0];
    }
}

// ---------------------------------------------------------------------------
// Row softmax over F=64 columns. One 64-lane wave per row, 4 rows per block.
// ---------------------------------------------------------------------------
__global__ __launch_bounds__(256) void softmax64(float* __restrict__ out) {
    int row = blockIdx.x * 4 + (threadIdx.x >> 6);
    int lane = threadIdx.x & 63;
    if (row >= N_NODES) return;
    long idx = (long)row * 64 + lane;
    float x = out[idx];
    float m = x;
#pragma unroll
    for (int off = 32; off > 0; off >>= 1) m = fmaxf(m, __shfl_xor(m, off, 64));
    float e = expf(x - m);
    float s = e;
#pragma unroll
    for (int off = 32; off > 0; off >>= 1) s += __shfl_xor(s, off, 64);
    out[idx] = e / s;
}

extern "C" void kernel_launch(void* const* d_in, const int* in_sizes, int n_in,
                              void* d_out, int out_size, void* d_ws, size_t ws_size,
                              hipStream_t stream) {
    const float* X = (const float*)d_in[0];
    const int* erow = (const int*)d_in[1];
    const int* ecol = (const int*)d_in[2];
    const float* eval_ = (const float*)d_in[3];
    const float* W0 = (const float*)d_in[4];   // [128,256]
    const float* Wh0 = (const float*)d_in[5];  // [128,128]
    const float* W1 = (const float*)d_in[6];   // [64,128]
    float* out = (float*)d_out;                // [N,64]

    char* ws = (char*)d_ws;
    int* row_ptr = (int*)ws;
    ws += (((size_t)(N_NODES + 1) * sizeof(int)) + 255) & ~(size_t)255;
    float* bufA = (float*)ws;
    ws += (size_t)N_NODES * H_DIM * sizeof(float);
    float* bufB = (float*)ws;

    build_row_ptr<<<(N_NODES + 256) / 256, 256, 0, stream>>>(erow, row_ptr);

    dim3 g1((N_NODES + 63) / 64, 1);
    dim3 gs((N_NODES + 3) / 4, 1);

    // Layer 0: bufA = X @ W0^T  [N,128]
    gemm_mfma<128><<<g1, 256, 0, stream>>>(X, W0, bufA, N_NODES, C_DIM);
    // bufB = relu(A_hat @ bufA)
    spmm_wave<128, true><<<gs, 256, 0, stream>>>(row_ptr, ecol, eval_, bufA, bufB);

    // Hidden layer: bufA = bufB @ Wh0^T  [N,128]
    gemm_mfma<128><<<g1, 256, 0, stream>>>(bufB, Wh0, bufA, N_NODES, H_DIM);
    // bufB = relu(A_hat @ bufA)
    spmm_wave<128, true><<<gs, 256, 0, stream>>>(row_ptr, ecol, eval_, bufA, bufB);

    // Output layer: bufA = bufB @ W1^T  [N,64]
    gemm_mfma<64><<<g1, 256, 0, stream>>>(bufB, W1, bufA, N_NODES, H_DIM);
    // out = A_hat @ bufA
    spmm_wave<64, false><<<gs, 256, 0, stream>>>(row_ptr, ecol, eval_, bufA, out);

    softmax64<<<(N_NODES + 3) / 4, 256, 0, stream>>>(out);
}